// Round 10
// baseline (612.796 us; speedup 1.0000x reference)
//
#include <hip/hip_runtime.h>

// pred, target: [32,1,1024,1024] f32 -> scalar f32 = mean((softplus(p)-p*t)*w),
// w = 0.1 on 5x5 morphological gradient of binarized target, gated on
// cond = (t.max()==1 && t.min()==0).
//
// R9 resubmit (R9 bench was an infra failure; kernel never ran).
// DIAGNOSTIC ROUND. Scored kernel = exact R0 champion (119us, absmax 0.0).
// Added two probe dispatches sized (>119us) to surface in the top-5 counter
// table:
//   probe<0>: copy-shaped grid-stride read, 3 passes x (pred+target) = 804MB,
//             16 independent float4/thread/array, no LDS/barriers.
//   probe<1>: same + softplus per element (isolates transcendental cost).
// R8's key datum: L3-resident replays ran at identical dur to HBM-fed ones
// => kernels are neither BW- nor latency-bound; need the raw ceiling of a
// copy-shaped read on these buffers to locate the missing factor.

#define IMG     1024
#define BAND    32
#define NBANDS  (IMG / BAND)     // 32
#define NIMG    32
#define WORDS   16               // 1024 cols / 64 bits
#define HALO    2
#define MAXROWS (BAND + 2 * HALO)
#define NTOT    33554432.0
#define NTHREADS 524288          // probe: 2048 blocks x 256
#define NQ       8388608         // float4 per array

typedef unsigned long long u64;

__device__ __forceinline__ unsigned encf(float f) {
    unsigned u = __float_as_uint(f);
    return (u & 0x80000000u) ? ~u : (u | 0x80000000u);
}
__device__ __forceinline__ float decf(unsigned e) {
    unsigned u = (e & 0x80000000u) ? (e & 0x7fffffffu) : ~e;
    return __uint_as_float(u);
}
__device__ __forceinline__ float sum4(float4 v) { return (v.x + v.y) + (v.z + v.w); }
__device__ __forceinline__ float sp1(float x) {
    return fmaxf(x, 0.f) + __logf(1.f + __expf(-fabsf(x)));
}
__device__ __forceinline__ float sp4(float4 v) {
    return (sp1(v.x) + sp1(v.y)) + (sp1(v.z) + sp1(v.w));
}

__global__ void bbl_init(double* dws, unsigned* uws) {
    if (threadIdx.x == 0) {
        dws[0] = 0.0; dws[1] = 0.0;
        uws[0] = 0xFFFFFFFFu;   // running min (encoded)
        uws[1] = 0u;            // running max (encoded)
    }
}

// ---------------- diagnostic probes (results unused; sink prevents DCE) -----
template <int SP>
__global__ __launch_bounds__(256) void probe(const float* __restrict__ a,
                                             const float* __restrict__ b,
                                             float* __restrict__ sink) {
    const int tid = blockIdx.x * 256 + threadIdx.x;   // 0..524287
    float s = 0.f;
    #pragma unroll 1
    for (int pass = 0; pass < 3; ++pass) {
        #pragma unroll 1
        for (int arr = 0; arr < 2; ++arr) {
            const float4* P = (const float4*)(arr ? b : a);
            #pragma unroll 1
            for (int h = 0; h < 2; ++h) {             // 2 groups of 8 in-flight
                const int g0 = h * 8;
                float4 v0 = P[(size_t)(g0 + 0) * NTHREADS + tid];
                float4 v1 = P[(size_t)(g0 + 1) * NTHREADS + tid];
                float4 v2 = P[(size_t)(g0 + 2) * NTHREADS + tid];
                float4 v3 = P[(size_t)(g0 + 3) * NTHREADS + tid];
                float4 v4 = P[(size_t)(g0 + 4) * NTHREADS + tid];
                float4 v5 = P[(size_t)(g0 + 5) * NTHREADS + tid];
                float4 v6 = P[(size_t)(g0 + 6) * NTHREADS + tid];
                float4 v7 = P[(size_t)(g0 + 7) * NTHREADS + tid];
                if (SP) {
                    s += sp4(v0) + sp4(v1) + sp4(v2) + sp4(v3);
                    s += sp4(v4) + sp4(v5) + sp4(v6) + sp4(v7);
                } else {
                    s += sum4(v0) + sum4(v1) + sum4(v2) + sum4(v3);
                    s += sum4(v4) + sum4(v5) + sum4(v6) + sum4(v7);
                }
            }
        }
    }
    for (int off = 32; off > 0; off >>= 1) s += __shfl_down(s, off);
    if ((threadIdx.x & 63) == 0) atomicAdd(sink, s);
}

// ---------------- scored kernel: exact R0 champion --------------------------
__global__ __launch_bounds__(512) void bbl_main(
        const float* __restrict__ pred,
        const float* __restrict__ target,
        double* __restrict__ dws, unsigned* __restrict__ uws) {
    __shared__ u64 Bm[MAXROWS][WORDS];   // raw bits (t>0.5), interleaved layout
    __shared__ u64 Vd[BAND][WORDS];      // vertical OR  (dilate, 5 rows)
    __shared__ u64 Ve[BAND][WORDS];      // vertical AND (erode, 5 rows)
    __shared__ u64 Em[BAND][WORDS];      // edge bits
    __shared__ float    redS1[8], redSe[8];
    __shared__ unsigned redMn[8], redMx[8];

    const int tid  = threadIdx.x;
    const int lane = tid & 63;
    const int wid  = tid >> 6;           // 8 waves
    const int img  = blockIdx.x / NBANDS;
    const int r0   = (blockIdx.x % NBANDS) * BAND;
    const int hs   = max(r0 - HALO, 0);
    const int he   = min(r0 + BAND + HALO, IMG);
    const int nLoaded = he - hs;
    const size_t base = (size_t)img * IMG * IMG;

    float vmin = 3.4e38f, vmax = -3.4e38f;

    // ---- 1a: stream target rows (band+halo) as float4; ballot -> mask words
    for (int lr = wid; lr < nLoaded; lr += 8) {
        const float4* rowp = (const float4*)(target + base + (size_t)(hs + lr) * IMG);
        #pragma unroll
        for (int it = 0; it < 4; ++it) {
            float4 v = rowp[it * 64 + lane];
            vmin = fminf(vmin, fminf(fminf(v.x, v.y), fminf(v.z, v.w)));
            vmax = fmaxf(vmax, fmaxf(fmaxf(v.x, v.y), fmaxf(v.z, v.w)));
            u64 b0 = __ballot(v.x > 0.5f);
            u64 b1 = __ballot(v.y > 0.5f);
            u64 b2 = __ballot(v.z > 0.5f);
            u64 b3 = __ballot(v.w > 0.5f);
            if (lane < 4) {
                u64 w = (lane == 0) ? b0 : (lane == 1) ? b1 : (lane == 2) ? b2 : b3;
                Bm[lr][it * 4 + lane] = w;
            }
        }
    }
    __syncthreads();

    // ---- 1b: vertical OR/AND over rows gr-2..gr+2 (clamped)
    {
        const int orow = tid >> 4, w = tid & 15;      // 32*16 = 512 = blockDim
        const int gr = r0 + orow;
        const int lo = max(gr - 2, 0), hi = min(gr + 2, IMG - 1);
        u64 vd = 0ULL, ve = ~0ULL;
        for (int g = lo; g <= hi; ++g) { u64 b = Bm[g - hs][w]; vd |= b; ve &= b; }
        Vd[orow][w] = vd; Ve[orow][w] = ve;
    }
    __syncthreads();

    // ---- 1c: horizontal +-2 in interleaved domain; edge = dilate & ~erode
    {
        const int orow = tid >> 4, w = tid & 15;
        const int k = w & 3;
        u64 hd = Vd[orow][w], he_ = Ve[orow][w];
        #pragma unroll
        for (int dd = 0; dd < 4; ++dd) {
            const int delta = (dd < 2) ? dd - 2 : dd - 1;  // -2,-1,1,2
            const int kp = k + delta;
            u64 td, te;
            if (kp >= 0 && kp <= 3) {               // same 256-block, aligned
                td = Vd[orow][w + delta];
                te = Ve[orow][w + delta];
            } else if (kp > 3) {                    // wraps toward next block
                const int wi = w + delta - 4, wn = w + delta;
                u64 nd = (wn <= 15) ? Vd[orow][wn] : 0ULL;   // OOB col: dilate id
                u64 ne = (wn <= 15) ? Ve[orow][wn] : ~0ULL;  // OOB col: erode id
                td = (Vd[orow][wi] >> 1) | (nd << 63);
                te = (Ve[orow][wi] >> 1) | (ne << 63);
            } else {                                // wraps toward prev block
                const int wi = w + delta + 4, wn = w + delta;
                u64 nd = (wn >= 0) ? Vd[orow][wn] : 0ULL;
                u64 ne = (wn >= 0) ? Ve[orow][wn] : ~0ULL;
                td = (Vd[orow][wi] << 1) | (nd >> 63);
                te = (Ve[orow][wi] << 1) | (ne >> 63);
            }
            hd |= td; he_ &= te;
        }
        Em[orow][w] = hd & ~he_;
    }
    __syncthreads();

    // ---- 2: stream pred float4; bits via LDS broadcast reads
    float s1 = 0.f, se = 0.f;
    for (int orow = wid * 4; orow < wid * 4 + 4; ++orow) {   // 8 waves x 4 rows
        const int gr = r0 + orow, lr = gr - hs;
        const float4* rowp = (const float4*)(pred + base + (size_t)gr * IMG);
        #pragma unroll
        for (int it = 0; it < 4; ++it) {
            float4 p = rowp[it * 64 + lane];
            u64 e0 = Em[orow][it * 4 + 0], e1 = Em[orow][it * 4 + 1];
            u64 e2 = Em[orow][it * 4 + 2], e3 = Em[orow][it * 4 + 3];
            u64 t0 = Bm[lr][it * 4 + 0],   t1 = Bm[lr][it * 4 + 1];
            u64 t2 = Bm[lr][it * 4 + 2],   t3 = Bm[lr][it * 4 + 3];
            float x, t, loss;
            x = p.x; t = (float)((unsigned)((t0 >> lane) & 1ULL));
            loss = fmaxf(x, 0.f) - x * t + __logf(1.f + __expf(-fabsf(x)));
            s1 += loss; se += ((e0 >> lane) & 1ULL) ? loss : 0.f;
            x = p.y; t = (float)((unsigned)((t1 >> lane) & 1ULL));
            loss = fmaxf(x, 0.f) - x * t + __logf(1.f + __expf(-fabsf(x)));
            s1 += loss; se += ((e1 >> lane) & 1ULL) ? loss : 0.f;
            x = p.z; t = (float)((unsigned)((t2 >> lane) & 1ULL));
            loss = fmaxf(x, 0.f) - x * t + __logf(1.f + __expf(-fabsf(x)));
            s1 += loss; se += ((e2 >> lane) & 1ULL) ? loss : 0.f;
            x = p.w; t = (float)((unsigned)((t3 >> lane) & 1ULL));
            loss = fmaxf(x, 0.f) - x * t + __logf(1.f + __expf(-fabsf(x)));
            s1 += loss; se += ((e3 >> lane) & 1ULL) ? loss : 0.f;
        }
    }

    // ---- reduce: wave shuffles, 8 waves via LDS, one atomic set per block
    for (int off = 32; off > 0; off >>= 1) {
        s1   += __shfl_down(s1, off);
        se   += __shfl_down(se, off);
        vmin  = fminf(vmin, __shfl_down(vmin, off));
        vmax  = fmaxf(vmax, __shfl_down(vmax, off));
    }
    if (lane == 0) {
        redS1[wid] = s1; redSe[wid] = se;
        redMn[wid] = encf(vmin); redMx[wid] = encf(vmax);
    }
    __syncthreads();
    if (tid == 0) {
        float S1 = 0.f, Se = 0.f; unsigned mn = 0xFFFFFFFFu, mx = 0u;
        #pragma unroll
        for (int i = 0; i < 8; ++i) {
            S1 += redS1[i]; Se += redSe[i];
            mn = min(mn, redMn[i]); mx = max(mx, redMx[i]);
        }
        atomicAdd(&dws[0], (double)S1);
        atomicAdd(&dws[1], (double)Se);
        atomicMin(&uws[0], mn);
        atomicMax(&uws[1], mx);
    }
}

__global__ void bbl_fin(const double* __restrict__ dws,
                        const unsigned* __restrict__ uws,
                        float* __restrict__ out) {
    if (threadIdx.x == 0) {
        float fmin = decf(uws[0]);
        float fmax = decf(uws[1]);
        bool cond = (fmax == 1.0f) && (fmin == 0.0f);
        double s = cond ? (dws[0] - 0.9 * dws[1]) : dws[0];
        out[0] = (float)(s / NTOT);
    }
}

extern "C" void kernel_launch(void* const* d_in, const int* in_sizes, int n_in,
                              void* d_out, int out_size, void* d_ws, size_t ws_size,
                              hipStream_t stream) {
    const float* pred   = (const float*)d_in[0];
    const float* target = (const float*)d_in[1];
    double*   dws = (double*)d_ws;
    unsigned* uws = (unsigned*)(dws + 2);
    float*    sink = (float*)((char*)d_ws + 32);   // scratch; value unused
    float*    out = (float*)d_out;

    hipLaunchKernelGGL(bbl_init, dim3(1), dim3(64), 0, stream, dws, uws);
    // diagnostic probes (do not affect output)
    hipLaunchKernelGGL((probe<0>), dim3(2048), dim3(256), 0, stream,
                       pred, target, sink);
    hipLaunchKernelGGL((probe<1>), dim3(2048), dim3(256), 0, stream,
                       pred, target, sink + 1);
    // scored computation (exact R0 champion)
    hipLaunchKernelGGL(bbl_main, dim3(NIMG * NBANDS), dim3(512), 0, stream,
                       pred, target, dws, uws);
    hipLaunchKernelGGL(bbl_fin, dim3(1), dim3(64), 0, stream, dws, uws, out);
}

// Round 12
// 297.692 us; speedup vs baseline: 2.0585x; 2.0585x over previous
//
#include <hip/hip_runtime.h>

// pred, target: [32,1,1024,1024] f32 -> scalar f32 = mean((softplus(p)-p*t)*w),
// w = 0.1 on 5x5 morphological gradient of binarized target, gated on
// cond = (t.max()==1 && t.min()==0).
//
// R11 resubmit (R11 bench was a GPU-acquisition timeout; kernel never ran).
// Probe-shaped streaming inside the champion fused structure.
// R10 probes measured: flat 8-deep back-to-back float4 bursts = 4.1 TB/s on
// these buffers (188us/804MB); softplus under the stream is FREE (probe<1>
// == probe<0>). Champion streams ran at 2.25 TB/s because ballot/LDS/loss ops
// were interleaved between loads. Changes:
//   - both stream phases now issue 8 float4 (two rows x 4 groups) back-to-back
//     (#pragma unroll 1 pins burst depth), consume after.
//   - 256-thr blocks (4 waves), BAND=32 kept: if VGPR lands in 65..85 we still
//     get 6-7 blocks/CU (1024-block grid fully resident), avoiding the
//     512-thr 4->3 blocks/CU cliff that killed R6.
//   - phases 1b/1c loop x2 over rows; reduce uses 4 waves.
// Loss math identical to champion (absmax 0.0 expected).

#define IMG     1024
#define BAND    32
#define NBANDS  (IMG / BAND)     // 32
#define NIMG    32
#define WORDS   16               // 1024 cols / 64 bits
#define HALO    2
#define MAXROWS (BAND + 2 * HALO)
#define NTOT    33554432.0

typedef unsigned long long u64;

__device__ __forceinline__ unsigned encf(float f) {
    unsigned u = __float_as_uint(f);
    return (u & 0x80000000u) ? ~u : (u | 0x80000000u);
}
__device__ __forceinline__ float decf(unsigned e) {
    unsigned u = (e & 0x80000000u) ? (e & 0x7fffffffu) : ~e;
    return __uint_as_float(u);
}

__global__ void bbl_init(double* dws, unsigned* uws) {
    if (threadIdx.x == 0) {
        dws[0] = 0.0; dws[1] = 0.0;
        uws[0] = 0xFFFFFFFFu;   // running min (encoded)
        uws[1] = 0u;            // running max (encoded)
    }
}

__global__ __launch_bounds__(256) void bbl_main(
        const float* __restrict__ pred,
        const float* __restrict__ target,
        double* __restrict__ dws, unsigned* __restrict__ uws) {
    __shared__ u64 Bm[MAXROWS][WORDS];   // raw bits (t>0.5), interleaved layout
    __shared__ u64 Vd[BAND][WORDS];      // vertical OR  (dilate, 5 rows)
    __shared__ u64 Ve[BAND][WORDS];      // vertical AND (erode, 5 rows)
    __shared__ u64 Em[BAND][WORDS];      // edge bits
    __shared__ float    redS1[4], redSe[4];
    __shared__ unsigned redMn[4], redMx[4];

    const int tid  = threadIdx.x;
    const int lane = tid & 63;
    const int wid  = tid >> 6;           // 4 waves
    const int img  = blockIdx.x / NBANDS;
    const int r0   = (blockIdx.x % NBANDS) * BAND;
    const int hs   = max(r0 - HALO, 0);
    const int he   = min(r0 + BAND + HALO, IMG);
    const int nLoaded = he - hs;
    const size_t base = (size_t)img * IMG * IMG;
    const float* tb = target + base;

    float vmin = 3.4e38f, vmax = -3.4e38f;

    // ---- 1a: target stream; two rows per iter, 8 float4 issued back-to-back,
    //          then ballots -> mask words (word it*4+m holds cols
    //          256*it+4*lane+m at bit lane)
    #pragma unroll 1
    for (int lr = wid; lr < nLoaded; lr += 8) {
        const int lrB = lr + 4;
        const bool hb = (lrB < nLoaded);
        const float* rA = tb + (size_t)(hs + lr) * IMG + 4 * lane;
        float4 a0 = *(const float4*)(rA);
        float4 a1 = *(const float4*)(rA + 256);
        float4 a2 = *(const float4*)(rA + 512);
        float4 a3 = *(const float4*)(rA + 768);
        float4 d0, d1, d2, d3;
        if (hb) {
            const float* rB = tb + (size_t)(hs + lrB) * IMG + 4 * lane;
            d0 = *(const float4*)(rB);
            d1 = *(const float4*)(rB + 256);
            d2 = *(const float4*)(rB + 512);
            d3 = *(const float4*)(rB + 768);
        }
        #pragma unroll
        for (int it = 0; it < 4; ++it) {
            float4 v = (it == 0) ? a0 : (it == 1) ? a1 : (it == 2) ? a2 : a3;
            vmin = fminf(vmin, fminf(fminf(v.x, v.y), fminf(v.z, v.w)));
            vmax = fmaxf(vmax, fmaxf(fmaxf(v.x, v.y), fmaxf(v.z, v.w)));
            u64 c0 = __ballot(v.x > 0.5f);
            u64 c1 = __ballot(v.y > 0.5f);
            u64 c2 = __ballot(v.z > 0.5f);
            u64 c3 = __ballot(v.w > 0.5f);
            if (lane < 4) {
                u64 w = (lane == 0) ? c0 : (lane == 1) ? c1 : (lane == 2) ? c2 : c3;
                Bm[lr][it * 4 + lane] = w;
            }
        }
        if (hb) {
            #pragma unroll
            for (int it = 0; it < 4; ++it) {
                float4 v = (it == 0) ? d0 : (it == 1) ? d1 : (it == 2) ? d2 : d3;
                vmin = fminf(vmin, fminf(fminf(v.x, v.y), fminf(v.z, v.w)));
                vmax = fmaxf(vmax, fmaxf(fmaxf(v.x, v.y), fmaxf(v.z, v.w)));
                u64 c0 = __ballot(v.x > 0.5f);
                u64 c1 = __ballot(v.y > 0.5f);
                u64 c2 = __ballot(v.z > 0.5f);
                u64 c3 = __ballot(v.w > 0.5f);
                if (lane < 4) {
                    u64 w = (lane == 0) ? c0 : (lane == 1) ? c1 : (lane == 2) ? c2 : c3;
                    Bm[lrB][it * 4 + lane] = w;
                }
            }
        }
    }
    __syncthreads();

    // ---- 1b: vertical OR/AND over rows gr-2..gr+2 (clamped; skipped rows are
    //          identity, matching -inf/+inf reduce_window padding); x2 halves
    {
        const int w = tid & 15;
        #pragma unroll
        for (int half = 0; half < 2; ++half) {
            const int orow = (tid >> 4) + half * 16;   // 0..31
            const int gr = r0 + orow;
            const int lo = max(gr - 2, 0), hi = min(gr + 2, IMG - 1);
            u64 vd = 0ULL, ve = ~0ULL;
            for (int g = lo; g <= hi; ++g) { u64 bb = Bm[g - hs][w]; vd |= bb; ve &= bb; }
            Vd[orow][w] = vd; Ve[orow][w] = ve;
        }
    }
    __syncthreads();

    // ---- 1c: horizontal +-2 in interleaved domain; edge = dilate & ~erode
    {
        const int w = tid & 15;
        const int k = w & 3;
        #pragma unroll
        for (int half = 0; half < 2; ++half) {
            const int orow = (tid >> 4) + half * 16;
            u64 hd = Vd[orow][w], he_ = Ve[orow][w];
            #pragma unroll
            for (int dd = 0; dd < 4; ++dd) {
                const int delta = (dd < 2) ? dd - 2 : dd - 1;  // -2,-1,1,2
                const int kp = k + delta;
                u64 td, te;
                if (kp >= 0 && kp <= 3) {               // same 256-block, aligned
                    td = Vd[orow][w + delta];
                    te = Ve[orow][w + delta];
                } else if (kp > 3) {                    // wraps toward next block
                    const int wi = w + delta - 4, wn = w + delta;
                    u64 nd = (wn <= 15) ? Vd[orow][wn] : 0ULL;   // OOB: dilate id
                    u64 ne = (wn <= 15) ? Ve[orow][wn] : ~0ULL;  // OOB: erode id
                    td = (Vd[orow][wi] >> 1) | (nd << 63);
                    te = (Ve[orow][wi] >> 1) | (ne << 63);
                } else {                                // wraps toward prev block
                    const int wi = w + delta + 4, wn = w + delta;
                    u64 nd = (wn >= 0) ? Vd[orow][wn] : 0ULL;
                    u64 ne = (wn >= 0) ? Ve[orow][wn] : ~0ULL;
                    td = (Vd[orow][wi] << 1) | (nd >> 63);
                    te = (Ve[orow][wi] << 1) | (ne >> 63);
                }
                hd |= td; he_ &= te;
            }
            Em[orow][w] = hd & ~he_;
        }
    }
    __syncthreads();

    // ---- 2: pred stream; 4 waves x 8 rows; two rows per iter with 8 float4
    //         issued back-to-back, then loss math via LDS broadcast bits
    float s1 = 0.f, se = 0.f;
    const float* pb = pred + base;
    #pragma unroll 1
    for (int jp = 0; jp < 8; jp += 2) {
        const int oA = wid * 8 + jp, oB = oA + 1;
        const int lrA = r0 + oA - hs, lrB = r0 + oB - hs;
        const float* rA = pb + (size_t)(r0 + oA) * IMG + 4 * lane;
        const float* rB = pb + (size_t)(r0 + oB) * IMG + 4 * lane;
        float4 pA0 = *(const float4*)(rA);
        float4 pA1 = *(const float4*)(rA + 256);
        float4 pA2 = *(const float4*)(rA + 512);
        float4 pA3 = *(const float4*)(rA + 768);
        float4 pB0 = *(const float4*)(rB);
        float4 pB1 = *(const float4*)(rB + 256);
        float4 pB2 = *(const float4*)(rB + 512);
        float4 pB3 = *(const float4*)(rB + 768);
        #pragma unroll
        for (int it = 0; it < 4; ++it) {
            float4 p = (it == 0) ? pA0 : (it == 1) ? pA1 : (it == 2) ? pA2 : pA3;
            u64 e0 = Em[oA][it * 4 + 0], e1 = Em[oA][it * 4 + 1];
            u64 e2 = Em[oA][it * 4 + 2], e3 = Em[oA][it * 4 + 3];
            u64 t0 = Bm[lrA][it * 4 + 0], t1 = Bm[lrA][it * 4 + 1];
            u64 t2 = Bm[lrA][it * 4 + 2], t3 = Bm[lrA][it * 4 + 3];
            float x, t, loss;
            x = p.x; t = (float)((unsigned)((t0 >> lane) & 1ULL));
            loss = fmaxf(x, 0.f) - x * t + __logf(1.f + __expf(-fabsf(x)));
            s1 += loss; se += ((e0 >> lane) & 1ULL) ? loss : 0.f;
            x = p.y; t = (float)((unsigned)((t1 >> lane) & 1ULL));
            loss = fmaxf(x, 0.f) - x * t + __logf(1.f + __expf(-fabsf(x)));
            s1 += loss; se += ((e1 >> lane) & 1ULL) ? loss : 0.f;
            x = p.z; t = (float)((unsigned)((t2 >> lane) & 1ULL));
            loss = fmaxf(x, 0.f) - x * t + __logf(1.f + __expf(-fabsf(x)));
            s1 += loss; se += ((e2 >> lane) & 1ULL) ? loss : 0.f;
            x = p.w; t = (float)((unsigned)((t3 >> lane) & 1ULL));
            loss = fmaxf(x, 0.f) - x * t + __logf(1.f + __expf(-fabsf(x)));
            s1 += loss; se += ((e3 >> lane) & 1ULL) ? loss : 0.f;
        }
        #pragma unroll
        for (int it = 0; it < 4; ++it) {
            float4 p = (it == 0) ? pB0 : (it == 1) ? pB1 : (it == 2) ? pB2 : pB3;
            u64 e0 = Em[oB][it * 4 + 0], e1 = Em[oB][it * 4 + 1];
            u64 e2 = Em[oB][it * 4 + 2], e3 = Em[oB][it * 4 + 3];
            u64 t0 = Bm[lrB][it * 4 + 0], t1 = Bm[lrB][it * 4 + 1];
            u64 t2 = Bm[lrB][it * 4 + 2], t3 = Bm[lrB][it * 4 + 3];
            float x, t, loss;
            x = p.x; t = (float)((unsigned)((t0 >> lane) & 1ULL));
            loss = fmaxf(x, 0.f) - x * t + __logf(1.f + __expf(-fabsf(x)));
            s1 += loss; se += ((e0 >> lane) & 1ULL) ? loss : 0.f;
            x = p.y; t = (float)((unsigned)((t1 >> lane) & 1ULL));
            loss = fmaxf(x, 0.f) - x * t + __logf(1.f + __expf(-fabsf(x)));
            s1 += loss; se += ((e1 >> lane) & 1ULL) ? loss : 0.f;
            x = p.z; t = (float)((unsigned)((t2 >> lane) & 1ULL));
            loss = fmaxf(x, 0.f) - x * t + __logf(1.f + __expf(-fabsf(x)));
            s1 += loss; se += ((e2 >> lane) & 1ULL) ? loss : 0.f;
            x = p.w; t = (float)((unsigned)((t3 >> lane) & 1ULL));
            loss = fmaxf(x, 0.f) - x * t + __logf(1.f + __expf(-fabsf(x)));
            s1 += loss; se += ((e3 >> lane) & 1ULL) ? loss : 0.f;
        }
    }

    // ---- reduce: wave shuffles, 4 waves via LDS, one atomic set per block
    for (int off = 32; off > 0; off >>= 1) {
        s1   += __shfl_down(s1, off);
        se   += __shfl_down(se, off);
        vmin  = fminf(vmin, __shfl_down(vmin, off));
        vmax  = fmaxf(vmax, __shfl_down(vmax, off));
    }
    if (lane == 0) {
        redS1[wid] = s1; redSe[wid] = se;
        redMn[wid] = encf(vmin); redMx[wid] = encf(vmax);
    }
    __syncthreads();
    if (tid == 0) {
        float S1 = 0.f, Se = 0.f; unsigned mn = 0xFFFFFFFFu, mx = 0u;
        #pragma unroll
        for (int i = 0; i < 4; ++i) {
            S1 += redS1[i]; Se += redSe[i];
            mn = min(mn, redMn[i]); mx = max(mx, redMx[i]);
        }
        atomicAdd(&dws[0], (double)S1);
        atomicAdd(&dws[1], (double)Se);
        atomicMin(&uws[0], mn);
        atomicMax(&uws[1], mx);
    }
}

__global__ void bbl_fin(const double* __restrict__ dws,
                        const unsigned* __restrict__ uws,
                        float* __restrict__ out) {
    if (threadIdx.x == 0) {
        float fmin = decf(uws[0]);
        float fmax = decf(uws[1]);
        bool cond = (fmax == 1.0f) && (fmin == 0.0f);
        double s = cond ? (dws[0] - 0.9 * dws[1]) : dws[0];
        out[0] = (float)(s / NTOT);
    }
}

extern "C" void kernel_launch(void* const* d_in, const int* in_sizes, int n_in,
                              void* d_out, int out_size, void* d_ws, size_t ws_size,
                              hipStream_t stream) {
    const float* pred   = (const float*)d_in[0];
    const float* target = (const float*)d_in[1];
    double*   dws = (double*)d_ws;
    unsigned* uws = (unsigned*)(dws + 2);
    float*    out = (float*)d_out;

    hipLaunchKernelGGL(bbl_init, dim3(1), dim3(64), 0, stream, dws, uws);
    hipLaunchKernelGGL(bbl_main, dim3(NIMG * NBANDS), dim3(256), 0, stream,
                       pred, target, dws, uws);
    hipLaunchKernelGGL(bbl_fin, dim3(1), dim3(64), 0, stream, dws, uws, out);
}